// Round 4
// baseline (1176.274 us; speedup 1.0000x reference)
//
#include <hip/hip_runtime.h>
#include <hip/hip_bf16.h>

// Problem constants (from reference)
#define NUM_USERS 100000
#define NUM_ITEMS 50000
#define N_NODES   150000   // NUM_USERS + NUM_ITEMS
#define EMB       64
#define NNZ       2400000
#define BATCH     16384
#define D_CAT     384      // EMB*3*2

// ---- bf16 helpers (bit-level, RN-even for f32->bf16) -----------------------
__device__ __forceinline__ unsigned short f2bf(float f) {
    unsigned u = __float_as_uint(f);
    unsigned r = u + 0x7fffu + ((u >> 16) & 1u);
    return (unsigned short)(r >> 16);
}
__device__ __forceinline__ float bflo(unsigned u) { return __uint_as_float(u << 16); }
__device__ __forceinline__ float bfhi(unsigned u) { return __uint_as_float(u & 0xffff0000u); }

// ---------------------------------------------------------------------------
// CSR build step 1: histogram of row indices. cnt must be zeroed first.
// ---------------------------------------------------------------------------
__global__ __launch_bounds__(256) void hist_rows(const int* __restrict__ rows,
                                                 int* __restrict__ cnt, int nnz) {
    int i = blockIdx.x * 256 + threadIdx.x;
    if (i < nnz) atomicAdd(&cnt[rows[i]], 1);
}

// ---------------------------------------------------------------------------
// CSR build step 2: single-block exclusive scan of cnt[n] -> row_ptr, offs.
// Each of 1024 threads serially scans a 147-element chunk; block-scan of the
// chunk sums; then writes running prefixes. cnt may alias offs (read chunk
// happens before any write due to the __syncthreads between phases).
// ---------------------------------------------------------------------------
__global__ __launch_bounds__(1024) void scan_all(const int* __restrict__ cnt,
                                                 int* __restrict__ row_ptr,
                                                 int* __restrict__ offs,
                                                 int n, int nnz) {
    __shared__ int s[1024];
    int t = threadIdx.x;
    const int per = (n + 1023) / 1024;       // 147
    int lo = t * per, hi = lo + per > n ? n : lo + per;
    int sum = 0;
    for (int i = lo; i < hi; ++i) sum += cnt[i];
    s[t] = sum;
    __syncthreads();
#pragma unroll
    for (int off = 1; off < 1024; off <<= 1) {
        int v = (t >= off) ? s[t - off] : 0;
        __syncthreads();
        s[t] += v;
        __syncthreads();
    }
    int run = s[t] - sum;                    // exclusive prefix of this chunk
    for (int i = lo; i < hi; ++i) {
        int c = cnt[i];
        row_ptr[i] = run;
        offs[i] = run;
        run += c;
    }
    if (t == 0) row_ptr[n] = nnz;
}

// ---------------------------------------------------------------------------
// CSR build step 3: scatter (col, val) pairs into row-sorted packed array.
// ---------------------------------------------------------------------------
__global__ __launch_bounds__(256) void scatter_edges(const int* __restrict__ rows,
                                                     const int* __restrict__ cols,
                                                     const float* __restrict__ vals,
                                                     int* __restrict__ offs,
                                                     int2* __restrict__ packed, int nnz) {
    int i = blockIdx.x * 256 + threadIdx.x;
    if (i >= nnz) return;
    int r = rows[i];
    int pos = atomicAdd(&offs[r], 1);
    packed[pos] = make_int2(cols[i], __float_as_int(vals[i]));
}

// ---------------------------------------------------------------------------
// Convert concat(uEmb,iEmb) fp32 -> bf16 table (4 elems / thread)
// ---------------------------------------------------------------------------
__global__ __launch_bounds__(256) void cvt_feat0(const float4* __restrict__ a, int na4,
                                                 const float4* __restrict__ b, int nb4,
                                                 ushort4* __restrict__ dst) {
    int i = blockIdx.x * 256 + threadIdx.x;
    if (i >= na4 + nb4) return;
    float4 v = (i < na4) ? a[i] : b[i - na4];
    ushort4 o;
    o.x = f2bf(v.x); o.y = f2bf(v.y); o.z = f2bf(v.z); o.w = f2bf(v.w);
    dst[i] = o;
}

// ---------------------------------------------------------------------------
// SPMM (CSR): h[r] = x[r] + sum_edges v * x[c]  (bf16 gathers, fp32 acc).
// One wave per row; half-wave per edge (lanes 0-31 even edges, 32-63 odd).
// Each lane holds 2 row elements (bf16x2 = one uint). Cross-half reduce at
// the end via __shfl_xor(.,32); lanes 0-31 store the fp32 row.
// ---------------------------------------------------------------------------
__global__ __launch_bounds__(256) void spmm_csr(const int* __restrict__ row_ptr,
                                                const int2* __restrict__ packed,
                                                const unsigned int* __restrict__ xh, // bf16x2, stride 32/row
                                                float2* __restrict__ h,              // stride 32/row
                                                int n_rows) {
    int tid = threadIdx.x;
    int lane = tid & 63;
    int wave = tid >> 6;
    int half = lane >> 5;
    int k = lane & 31;
    int r = blockIdx.x * 4 + wave;
    if (r >= n_rows) return;

    // self loop (counted once, by half 0)
    unsigned su = xh[(size_t)r * 32 + k];
    float2 acc;
    acc.x = half ? 0.f : bflo(su);
    acc.y = half ? 0.f : bfhi(su);

    int e = row_ptr[r] + half;
    int end = row_ptr[r + 1];
    // 4-deep pipeline per half (8 edges in flight per wave)
    for (; e + 6 < end; e += 8) {
        int2 p0 = packed[e + 0];
        int2 p1 = packed[e + 2];
        int2 p2 = packed[e + 4];
        int2 p3 = packed[e + 6];
        unsigned x0 = xh[(size_t)p0.x * 32 + k];
        unsigned x1 = xh[(size_t)p1.x * 32 + k];
        unsigned x2 = xh[(size_t)p2.x * 32 + k];
        unsigned x3 = xh[(size_t)p3.x * 32 + k];
        float v0 = __int_as_float(p0.y), v1 = __int_as_float(p1.y);
        float v2 = __int_as_float(p2.y), v3 = __int_as_float(p3.y);
        acc.x = fmaf(v0, bflo(x0), acc.x); acc.y = fmaf(v0, bfhi(x0), acc.y);
        acc.x = fmaf(v1, bflo(x1), acc.x); acc.y = fmaf(v1, bfhi(x1), acc.y);
        acc.x = fmaf(v2, bflo(x2), acc.x); acc.y = fmaf(v2, bfhi(x2), acc.y);
        acc.x = fmaf(v3, bflo(x3), acc.x); acc.y = fmaf(v3, bfhi(x3), acc.y);
    }
    for (; e < end; e += 2) {
        int2 p = packed[e];
        unsigned x = xh[(size_t)p.x * 32 + k];
        float v = __int_as_float(p.y);
        acc.x = fmaf(v, bflo(x), acc.x);
        acc.y = fmaf(v, bfhi(x), acc.y);
    }

    // combine halves
    acc.x += __shfl_xor(acc.x, 32, 64);
    acc.y += __shfl_xor(acc.y, 32, 64);
    if (!half) h[(size_t)r * 32 + k] = acc;
}

// ---------------------------------------------------------------------------
// out_bf16[r][c] = relu( b[c] + sum_{k<64} X[r][k] * W[k][c] )
// Register-blocked: 4 waves/block, 16 rows/wave; lane = col. W in LDS.
// X rows read as wave-uniform float4 broadcasts.
// ---------------------------------------------------------------------------
__global__ __launch_bounds__(256) void gemm64_relu_bf16(const float* __restrict__ X,
                                                        const float* __restrict__ W,
                                                        const float* __restrict__ bia,
                                                        unsigned short* __restrict__ outh,
                                                        int n_rows) {
    __shared__ float Wl[64 * 64];
    int tid = threadIdx.x;
    int lane = tid & 63;
    int wave = tid >> 6;
    int r0 = blockIdx.x * 64 + wave * 16;
    int last = n_rows - 1;
    for (int i = tid; i < 64 * 64; i += 256) Wl[i] = W[i];
    __syncthreads();

    const float* rowp[16];
#pragma unroll
    for (int i = 0; i < 16; ++i) {
        int r = r0 + i;
        r = r > last ? last : r;
        rowp[i] = X + (size_t)r * 64;
    }
    float acc[16];
    float bv = bia[lane];
#pragma unroll
    for (int i = 0; i < 16; ++i) acc[i] = bv;

#pragma unroll 1
    for (int k = 0; k < 64; k += 4) {
        float w0 = Wl[(k + 0) * 64 + lane];
        float w1 = Wl[(k + 1) * 64 + lane];
        float w2 = Wl[(k + 2) * 64 + lane];
        float w3 = Wl[(k + 3) * 64 + lane];
#pragma unroll
        for (int i = 0; i < 16; ++i) {
            float4 e = *(const float4*)(rowp[i] + k);
            acc[i] = fmaf(e.x, w0, acc[i]);
            acc[i] = fmaf(e.y, w1, acc[i]);
            acc[i] = fmaf(e.z, w2, acc[i]);
            acc[i] = fmaf(e.w, w3, acc[i]);
        }
    }
#pragma unroll
    for (int i = 0; i < 16; ++i) {
        int r = r0 + i;
        if (r < n_rows) outh[(size_t)r * 64 + lane] = f2bf(fmaxf(acc[i], 0.f));
    }
}

// ---------------------------------------------------------------------------
// Gather concatenated per-sample features -> bf16 E (one 384-thread block/row)
// ---------------------------------------------------------------------------
__global__ __launch_bounds__(384) void gather_e(const int* __restrict__ userIdx,
                                                const int* __restrict__ itemIdx,
                                                const float* __restrict__ uEmb,
                                                const float* __restrict__ iEmb,
                                                const unsigned short* __restrict__ feat1h,
                                                const unsigned short* __restrict__ feat2h,
                                                unsigned short* __restrict__ E) {
    int b = blockIdx.x;
    int j = threadIdx.x;          // 0..383
    int half = j >= 192;
    int jj = half ? (j - 192) : j;
    int seg = jj >> 6;
    int k = jj & 63;
    unsigned short v;
    if (half == 0) {
        int u = userIdx[b];
        if (seg == 0)      v = f2bf(uEmb[(size_t)u * 64 + k]);
        else if (seg == 1) v = feat1h[(size_t)u * 64 + k];
        else               v = feat2h[(size_t)u * 64 + k];
    } else {
        int it = itemIdx[b];
        if (seg == 0)      v = f2bf(iEmb[(size_t)it * 64 + k]);
        else if (seg == 1) v = feat1h[(size_t)(it + NUM_USERS) * 64 + k];
        else               v = feat2h[(size_t)(it + NUM_USERS) * 64 + k];
    }
    E[(size_t)b * D_CAT + j] = v;
}

// ---------------------------------------------------------------------------
// H1[r][c] = relu( b1[c] + sum_{k<384} E[r][k] * W1[k][c] ), E bf16.
// 4 waves/block, 16 rows/wave; W1 fp32 staged in LDS in 128-row chunks.
// E rows read as wave-uniform uint4 broadcasts (8 bf16 each).
// ---------------------------------------------------------------------------
__global__ __launch_bounds__(256) void gemm384_bf16_relu(const unsigned short* __restrict__ E,
                                                         const float* __restrict__ W,
                                                         const float* __restrict__ bia,
                                                         float* __restrict__ H1,
                                                         int n_rows) {
    __shared__ float Wl[128 * 64];   // 32 KB
    int tid = threadIdx.x;
    int lane = tid & 63;
    int wave = tid >> 6;
    int r0 = blockIdx.x * 64 + wave * 16;
    int last = n_rows - 1;

    const unsigned short* rowp[16];
#pragma unroll
    for (int i = 0; i < 16; ++i) {
        int r = r0 + i;
        r = r > last ? last : r;
        rowp[i] = E + (size_t)r * D_CAT;
    }
    float acc[16];
    float bv = bia[lane];
#pragma unroll
    for (int i = 0; i < 16; ++i) acc[i] = bv;

    for (int k0 = 0; k0 < D_CAT; k0 += 128) {
        if (k0) __syncthreads();
        for (int i = tid; i < 128 * 64; i += 256) Wl[i] = W[k0 * 64 + i];
        __syncthreads();
#pragma unroll 1
        for (int k = 0; k < 128; k += 8) {
            float w0 = Wl[(k + 0) * 64 + lane];
            float w1 = Wl[(k + 1) * 64 + lane];
            float w2 = Wl[(k + 2) * 64 + lane];
            float w3 = Wl[(k + 3) * 64 + lane];
            float w4 = Wl[(k + 4) * 64 + lane];
            float w5 = Wl[(k + 5) * 64 + lane];
            float w6 = Wl[(k + 6) * 64 + lane];
            float w7 = Wl[(k + 7) * 64 + lane];
#pragma unroll
            for (int i = 0; i < 16; ++i) {
                uint4 q = *(const uint4*)(rowp[i] + k0 + k);
                acc[i] = fmaf(bflo(q.x), w0, acc[i]);
                acc[i] = fmaf(bfhi(q.x), w1, acc[i]);
                acc[i] = fmaf(bflo(q.y), w2, acc[i]);
                acc[i] = fmaf(bfhi(q.y), w3, acc[i]);
                acc[i] = fmaf(bflo(q.z), w4, acc[i]);
                acc[i] = fmaf(bfhi(q.z), w5, acc[i]);
                acc[i] = fmaf(bflo(q.w), w6, acc[i]);
                acc[i] = fmaf(bfhi(q.w), w7, acc[i]);
            }
        }
    }
#pragma unroll
    for (int i = 0; i < 16; ++i) {
        int r = r0 + i;
        if (r < n_rows) H1[(size_t)r * 64 + lane] = fmaxf(acc[i], 0.f);
    }
}

// ---------------------------------------------------------------------------
// Fused last two layers: z = H1@W2 + b2 (no relu); out = z@W3 + b3
// ---------------------------------------------------------------------------
__global__ __launch_bounds__(256) void mlp23(const float* __restrict__ H1,
                                             const float* __restrict__ W2,
                                             const float* __restrict__ b2,
                                             const float* __restrict__ W3,
                                             const float* __restrict__ b3,
                                             float* __restrict__ out) {
    __shared__ float Wl[64 * 32];
    __shared__ float w3l[32];
    __shared__ float b2l[32];
    int tid = threadIdx.x;
    for (int i = tid; i < 64 * 32; i += 256) Wl[i] = W2[i];
    if (tid < 32) { w3l[tid] = W3[tid]; b2l[tid] = b2[tid]; }
    __syncthreads();

    int lane = tid & 63;
    int wave = tid >> 6;
    int half = lane >> 5;
    int k = lane & 31;
    int gpair = blockIdx.x * 4 + wave;
    int npairs = gridDim.x * 4;
    float b3v = b3[0];
    for (int p = gpair; p * 2 < BATCH; p += npairs) {
        int r = p * 2 + half;
        float acc = b2l[k];
#pragma unroll
        for (int j = 0; j < 64; ++j)
            acc += H1[(size_t)r * 64 + j] * Wl[j * 32 + k];
        acc = acc * w3l[k];
#pragma unroll
        for (int off = 16; off; off >>= 1)
            acc += __shfl_xor(acc, off, 64);
        if (k == 0) out[r] = acc + b3v;
    }
}

// ---------------------------------------------------------------------------
extern "C" void kernel_launch(void* const* d_in, const int* in_sizes, int n_in,
                              void* d_out, int out_size, void* d_ws, size_t ws_size,
                              hipStream_t stream) {
    const int*   userIdx = (const int*)  d_in[0];
    const int*   itemIdx = (const int*)  d_in[1];
    const int*   lap_rows= (const int*)  d_in[2];
    const int*   lap_cols= (const int*)  d_in[3];
    const float* lap_vals= (const float*)d_in[4];
    const float* uEmb    = (const float*)d_in[5];
    const float* iEmb    = (const float*)d_in[6];
    const float* gW0     = (const float*)d_in[7];
    const float* gb0     = (const float*)d_in[8];
    const float* gW1     = (const float*)d_in[9];
    const float* gb1     = (const float*)d_in[10];
    const float* W1      = (const float*)d_in[11];
    const float* b1      = (const float*)d_in[12];
    const float* W2      = (const float*)d_in[13];
    const float* b2      = (const float*)d_in[14];
    const float* W3      = (const float*)d_in[15];
    const float* b3      = (const float*)d_in[16];
    float* out = (float*)d_out;

    const size_t NF = (size_t)N_NODES * EMB;              // 9.6M elements
    char* w = (char*)d_ws;
    unsigned short* bufA = (unsigned short*)w;            // feat0h then feat1h (19.2 MB)
    unsigned short* bufB = bufA + NF;                     // feat2h (19.2 MB)
    float* h       = (float*)(bufB + NF);                 // fp32 [N_NODES,64] (38.4 MB)
    int2*  packed  = (int2*)(h + NF);                     // 19.2 MB
    int*   row_ptr = (int*)(packed + NNZ);                // N_NODES+1
    int*   offs    = row_ptr + (N_NODES + 1);             // N_NODES
    // E/H1 overlay h (h dead after second gemm64)
    unsigned short* E  = (unsigned short*)h;              // [BATCH,384] bf16 (12.6 MB)
    float* H1 = (float*)(E + (size_t)BATCH * D_CAT);      // [BATCH,64] fp32

    const int edge_grid = (NNZ + 255) / 256;              // 9375
    const int spmm_grid = (N_NODES + 3) / 4;              // 37500
    const int gemm_grid = (N_NODES + 63) / 64;            // 2344
    const int cvt_grid  = (int)((NF / 4 + 255) / 256);    // 9375

    // ---- Build CSR (shared by both layers)
    hipMemsetAsync(offs, 0, N_NODES * sizeof(int), stream);
    hist_rows<<<edge_grid, 256, 0, stream>>>(lap_rows, offs, NNZ);
    scan_all<<<1, 1024, 0, stream>>>(offs, row_ptr, offs, N_NODES, NNZ);
    scatter_edges<<<edge_grid, 256, 0, stream>>>(lap_rows, lap_cols, lap_vals,
                                                 offs, packed, NNZ);

    // ---- feat0h = bf16(concat(uEmb, iEmb))
    cvt_feat0<<<cvt_grid, 256, 0, stream>>>((const float4*)uEmb, NUM_USERS * EMB / 4,
                                            (const float4*)iEmb, NUM_ITEMS * EMB / 4,
                                            (ushort4*)bufA);

    // ---- Layer 1: h = (L+I)@feat0 ; feat1h = bf16(relu(h@gW0+gb0))  (feat1h overwrites feat0h)
    spmm_csr<<<spmm_grid, 256, 0, stream>>>(row_ptr, packed, (const unsigned int*)bufA,
                                            (float2*)h, N_NODES);
    gemm64_relu_bf16<<<gemm_grid, 256, 0, stream>>>(h, gW0, gb0, bufA, N_NODES);

    // ---- Layer 2: h = (L+I)@feat1 ; feat2h = bf16(relu(h@gW1+gb1))
    spmm_csr<<<spmm_grid, 256, 0, stream>>>(row_ptr, packed, (const unsigned int*)bufA,
                                            (float2*)h, N_NODES);
    gemm64_relu_bf16<<<gemm_grid, 256, 0, stream>>>(h, gW1, gb1, bufB, N_NODES);

    // ---- Gather per-sample concatenated features (E overlays h)
    gather_e<<<BATCH, 384, 0, stream>>>(userIdx, itemIdx, uEmb, iEmb, bufA, bufB, E);

    // ---- MLP
    gemm384_bf16_relu<<<(BATCH + 63) / 64, 256, 0, stream>>>(E, W1, b1, H1, BATCH);
    mlp23<<<512, 256, 0, stream>>>(H1, W2, b2, W3, b3, out);
}

// Round 5
// 825.509 us; speedup vs baseline: 1.4249x; 1.4249x over previous
//
#include <hip/hip_runtime.h>
#include <hip/hip_bf16.h>

// Problem constants (from reference)
#define NUM_USERS 100000
#define NUM_ITEMS 50000
#define N_NODES   150000   // NUM_USERS + NUM_ITEMS
#define EMB       64
#define NNZ       2400000
#define BATCH     16384
#define D_CAT     384      // EMB*3*2

// ---- bf16 helpers (bit-level, RN-even for f32->bf16) -----------------------
__device__ __forceinline__ unsigned short f2bf(float f) {
    unsigned u = __float_as_uint(f);
    unsigned r = u + 0x7fffu + ((u >> 16) & 1u);
    return (unsigned short)(r >> 16);
}
__device__ __forceinline__ float bflo(unsigned u) { return __uint_as_float(u << 16); }
__device__ __forceinline__ float bfhi(unsigned u) { return __uint_as_float(u & 0xffff0000u); }

// ---------------------------------------------------------------------------
// CSR build step 1: histogram of row indices. cnt must be zeroed first.
// ---------------------------------------------------------------------------
__global__ __launch_bounds__(256) void hist_rows(const int* __restrict__ rows,
                                                 int* __restrict__ cnt, int nnz) {
    int i = blockIdx.x * 256 + threadIdx.x;
    if (i < nnz) atomicAdd(&cnt[rows[i]], 1);
}

// ---------------------------------------------------------------------------
// CSR build step 2a: per-block (1024-elem) exclusive scan of cnt -> partial,
// block totals -> blockSums. partial stored into row_ptr (temporarily).
// (Measured fast in round 3; round 4's single-block scan_all was 339 us.)
// ---------------------------------------------------------------------------
__global__ __launch_bounds__(1024) void scan1(const int* __restrict__ cnt,
                                              int* __restrict__ partial,
                                              int* __restrict__ blockSums, int n) {
    __shared__ int s[1024];
    int t = threadIdx.x;
    int i = blockIdx.x * 1024 + t;
    int x = (i < n) ? cnt[i] : 0;
    s[t] = x;
    __syncthreads();
#pragma unroll
    for (int off = 1; off < 1024; off <<= 1) {
        int v = (t >= off) ? s[t - off] : 0;
        __syncthreads();
        s[t] += v;
        __syncthreads();
    }
    if (i < n) partial[i] = s[t] - x;          // exclusive within block
    if (t == 1023) blockSums[blockIdx.x] = s[t];
}

// ---------------------------------------------------------------------------
// CSR build step 2b: single-block exclusive scan of blockSums (in place).
// ---------------------------------------------------------------------------
__global__ __launch_bounds__(1024) void scan2(int* __restrict__ blockSums, int nb) {
    __shared__ int s[1024];
    int t = threadIdx.x;
    int x = (t < nb) ? blockSums[t] : 0;
    s[t] = x;
    __syncthreads();
#pragma unroll
    for (int off = 1; off < 1024; off <<= 1) {
        int v = (t >= off) ? s[t - off] : 0;
        __syncthreads();
        s[t] += v;
        __syncthreads();
    }
    if (t < nb) blockSums[t] = s[t] - x;       // exclusive
}

// ---------------------------------------------------------------------------
// CSR build step 2c: row_ptr[i] = partial[i] + blockOffs[blk]; offs copy too.
// Also writes row_ptr[n] = nnz.
// ---------------------------------------------------------------------------
__global__ __launch_bounds__(1024) void scan3(int* __restrict__ row_ptr,
                                              int* __restrict__ offs,
                                              const int* __restrict__ blockSums,
                                              int n, int nnz) {
    int t = threadIdx.x;
    int i = blockIdx.x * 1024 + t;
    if (i < n) {
        int v = row_ptr[i] + blockSums[blockIdx.x];
        row_ptr[i] = v;
        offs[i] = v;
    }
    if (i == 0) row_ptr[n] = nnz;
}

// ---------------------------------------------------------------------------
// CSR build step 3: scatter (col, val) pairs into row-sorted packed array.
// ---------------------------------------------------------------------------
__global__ __launch_bounds__(256) void scatter_edges(const int* __restrict__ rows,
                                                     const int* __restrict__ cols,
                                                     const float* __restrict__ vals,
                                                     int* __restrict__ offs,
                                                     int2* __restrict__ packed, int nnz) {
    int i = blockIdx.x * 256 + threadIdx.x;
    if (i >= nnz) return;
    int r = rows[i];
    int pos = atomicAdd(&offs[r], 1);
    packed[pos] = make_int2(cols[i], __float_as_int(vals[i]));
}

// ---------------------------------------------------------------------------
// Convert concat(uEmb,iEmb) fp32 -> bf16 table (4 elems / thread)
// ---------------------------------------------------------------------------
__global__ __launch_bounds__(256) void cvt_feat0(const float4* __restrict__ a, int na4,
                                                 const float4* __restrict__ b, int nb4,
                                                 ushort4* __restrict__ dst) {
    int i = blockIdx.x * 256 + threadIdx.x;
    if (i >= na4 + nb4) return;
    float4 v = (i < na4) ? a[i] : b[i - na4];
    ushort4 o;
    o.x = f2bf(v.x); o.y = f2bf(v.y); o.z = f2bf(v.z); o.w = f2bf(v.w);
    dst[i] = o;
}

// ---------------------------------------------------------------------------
// SPMM (CSR): h[r] = x[r] + sum_edges v * x[c]  (bf16 gathers, fp32 acc).
// One wave per row; half-wave per edge (lanes 0-31 even edges, 32-63 odd).
// Each lane holds 2 row elements (bf16x2 = one uint). Cross-half reduce at
// the end via __shfl_xor(.,32); lanes 0-31 store the fp32 row.
// ---------------------------------------------------------------------------
__global__ __launch_bounds__(256) void spmm_csr(const int* __restrict__ row_ptr,
                                                const int2* __restrict__ packed,
                                                const unsigned int* __restrict__ xh, // bf16x2, stride 32/row
                                                float2* __restrict__ h,              // stride 32/row
                                                int n_rows) {
    int tid = threadIdx.x;
    int lane = tid & 63;
    int wave = tid >> 6;
    int half = lane >> 5;
    int k = lane & 31;
    int r = blockIdx.x * 4 + wave;
    if (r >= n_rows) return;

    // self loop (counted once, by half 0)
    unsigned su = xh[(size_t)r * 32 + k];
    float2 acc;
    acc.x = half ? 0.f : bflo(su);
    acc.y = half ? 0.f : bfhi(su);

    int e = row_ptr[r] + half;
    int end = row_ptr[r + 1];
    // 4-deep pipeline per half (8 edges in flight per wave)
    for (; e + 6 < end; e += 8) {
        int2 p0 = packed[e + 0];
        int2 p1 = packed[e + 2];
        int2 p2 = packed[e + 4];
        int2 p3 = packed[e + 6];
        unsigned x0 = xh[(size_t)p0.x * 32 + k];
        unsigned x1 = xh[(size_t)p1.x * 32 + k];
        unsigned x2 = xh[(size_t)p2.x * 32 + k];
        unsigned x3 = xh[(size_t)p3.x * 32 + k];
        float v0 = __int_as_float(p0.y), v1 = __int_as_float(p1.y);
        float v2 = __int_as_float(p2.y), v3 = __int_as_float(p3.y);
        acc.x = fmaf(v0, bflo(x0), acc.x); acc.y = fmaf(v0, bfhi(x0), acc.y);
        acc.x = fmaf(v1, bflo(x1), acc.x); acc.y = fmaf(v1, bfhi(x1), acc.y);
        acc.x = fmaf(v2, bflo(x2), acc.x); acc.y = fmaf(v2, bfhi(x2), acc.y);
        acc.x = fmaf(v3, bflo(x3), acc.x); acc.y = fmaf(v3, bfhi(x3), acc.y);
    }
    for (; e < end; e += 2) {
        int2 p = packed[e];
        unsigned x = xh[(size_t)p.x * 32 + k];
        float v = __int_as_float(p.y);
        acc.x = fmaf(v, bflo(x), acc.x);
        acc.y = fmaf(v, bfhi(x), acc.y);
    }

    // combine halves
    acc.x += __shfl_xor(acc.x, 32, 64);
    acc.y += __shfl_xor(acc.y, 32, 64);
    if (!half) h[(size_t)r * 32 + k] = acc;
}

// ---------------------------------------------------------------------------
// out_bf16[r][c] = relu( b[c] + sum_{k<64} X[r][k] * W[k][c] )
// Register-blocked: 4 waves/block, 16 rows/wave; lane = col. W in LDS.
// ---------------------------------------------------------------------------
__global__ __launch_bounds__(256) void gemm64_relu_bf16(const float* __restrict__ X,
                                                        const float* __restrict__ W,
                                                        const float* __restrict__ bia,
                                                        unsigned short* __restrict__ outh,
                                                        int n_rows) {
    __shared__ float Wl[64 * 64];
    int tid = threadIdx.x;
    int lane = tid & 63;
    int wave = tid >> 6;
    int r0 = blockIdx.x * 64 + wave * 16;
    int last = n_rows - 1;
    for (int i = tid; i < 64 * 64; i += 256) Wl[i] = W[i];
    __syncthreads();

    const float* rowp[16];
#pragma unroll
    for (int i = 0; i < 16; ++i) {
        int r = r0 + i;
        r = r > last ? last : r;
        rowp[i] = X + (size_t)r * 64;
    }
    float acc[16];
    float bv = bia[lane];
#pragma unroll
    for (int i = 0; i < 16; ++i) acc[i] = bv;

#pragma unroll 1
    for (int k = 0; k < 64; k += 4) {
        float w0 = Wl[(k + 0) * 64 + lane];
        float w1 = Wl[(k + 1) * 64 + lane];
        float w2 = Wl[(k + 2) * 64 + lane];
        float w3 = Wl[(k + 3) * 64 + lane];
#pragma unroll
        for (int i = 0; i < 16; ++i) {
            float4 e = *(const float4*)(rowp[i] + k);
            acc[i] = fmaf(e.x, w0, acc[i]);
            acc[i] = fmaf(e.y, w1, acc[i]);
            acc[i] = fmaf(e.z, w2, acc[i]);
            acc[i] = fmaf(e.w, w3, acc[i]);
        }
    }
#pragma unroll
    for (int i = 0; i < 16; ++i) {
        int r = r0 + i;
        if (r < n_rows) outh[(size_t)r * 64 + lane] = f2bf(fmaxf(acc[i], 0.f));
    }
}

// ---------------------------------------------------------------------------
// Gather concatenated per-sample features -> bf16 E (one 384-thread block/row)
// ---------------------------------------------------------------------------
__global__ __launch_bounds__(384) void gather_e(const int* __restrict__ userIdx,
                                                const int* __restrict__ itemIdx,
                                                const float* __restrict__ uEmb,
                                                const float* __restrict__ iEmb,
                                                const unsigned short* __restrict__ feat1h,
                                                const unsigned short* __restrict__ feat2h,
                                                unsigned short* __restrict__ E) {
    int b = blockIdx.x;
    int j = threadIdx.x;          // 0..383
    int half = j >= 192;
    int jj = half ? (j - 192) : j;
    int seg = jj >> 6;
    int k = jj & 63;
    unsigned short v;
    if (half == 0) {
        int u = userIdx[b];
        if (seg == 0)      v = f2bf(uEmb[(size_t)u * 64 + k]);
        else if (seg == 1) v = feat1h[(size_t)u * 64 + k];
        else               v = feat2h[(size_t)u * 64 + k];
    } else {
        int it = itemIdx[b];
        if (seg == 0)      v = f2bf(iEmb[(size_t)it * 64 + k]);
        else if (seg == 1) v = feat1h[(size_t)(it + NUM_USERS) * 64 + k];
        else               v = feat2h[(size_t)(it + NUM_USERS) * 64 + k];
    }
    E[(size_t)b * D_CAT + j] = v;
}

// ---------------------------------------------------------------------------
// H1[r][c] = relu( b1[c] + sum_{k<384} E[r][k] * W1[k][c] ), E bf16.
// ---------------------------------------------------------------------------
__global__ __launch_bounds__(256) void gemm384_bf16_relu(const unsigned short* __restrict__ E,
                                                         const float* __restrict__ W,
                                                         const float* __restrict__ bia,
                                                         float* __restrict__ H1,
                                                         int n_rows) {
    __shared__ float Wl[128 * 64];   // 32 KB
    int tid = threadIdx.x;
    int lane = tid & 63;
    int wave = tid >> 6;
    int r0 = blockIdx.x * 64 + wave * 16;
    int last = n_rows - 1;

    const unsigned short* rowp[16];
#pragma unroll
    for (int i = 0; i < 16; ++i) {
        int r = r0 + i;
        r = r > last ? last : r;
        rowp[i] = E + (size_t)r * D_CAT;
    }
    float acc[16];
    float bv = bia[lane];
#pragma unroll
    for (int i = 0; i < 16; ++i) acc[i] = bv;

    for (int k0 = 0; k0 < D_CAT; k0 += 128) {
        if (k0) __syncthreads();
        for (int i = tid; i < 128 * 64; i += 256) Wl[i] = W[k0 * 64 + i];
        __syncthreads();
#pragma unroll 1
        for (int k = 0; k < 128; k += 8) {
            float w0 = Wl[(k + 0) * 64 + lane];
            float w1 = Wl[(k + 1) * 64 + lane];
            float w2 = Wl[(k + 2) * 64 + lane];
            float w3 = Wl[(k + 3) * 64 + lane];
            float w4 = Wl[(k + 4) * 64 + lane];
            float w5 = Wl[(k + 5) * 64 + lane];
            float w6 = Wl[(k + 6) * 64 + lane];
            float w7 = Wl[(k + 7) * 64 + lane];
#pragma unroll
            for (int i = 0; i < 16; ++i) {
                uint4 q = *(const uint4*)(rowp[i] + k0 + k);
                acc[i] = fmaf(bflo(q.x), w0, acc[i]);
                acc[i] = fmaf(bfhi(q.x), w1, acc[i]);
                acc[i] = fmaf(bflo(q.y), w2, acc[i]);
                acc[i] = fmaf(bfhi(q.y), w3, acc[i]);
                acc[i] = fmaf(bflo(q.z), w4, acc[i]);
                acc[i] = fmaf(bfhi(q.z), w5, acc[i]);
                acc[i] = fmaf(bflo(q.w), w6, acc[i]);
                acc[i] = fmaf(bfhi(q.w), w7, acc[i]);
            }
        }
    }
#pragma unroll
    for (int i = 0; i < 16; ++i) {
        int r = r0 + i;
        if (r < n_rows) H1[(size_t)r * 64 + lane] = fmaxf(acc[i], 0.f);
    }
}

// ---------------------------------------------------------------------------
// Fused last two layers: z = H1@W2 + b2 (no relu); out = z@W3 + b3
// ---------------------------------------------------------------------------
__global__ __launch_bounds__(256) void mlp23(const float* __restrict__ H1,
                                             const float* __restrict__ W2,
                                             const float* __restrict__ b2,
                                             const float* __restrict__ W3,
                                             const float* __restrict__ b3,
                                             float* __restrict__ out) {
    __shared__ float Wl[64 * 32];
    __shared__ float w3l[32];
    __shared__ float b2l[32];
    int tid = threadIdx.x;
    for (int i = tid; i < 64 * 32; i += 256) Wl[i] = W2[i];
    if (tid < 32) { w3l[tid] = W3[tid]; b2l[tid] = b2[tid]; }
    __syncthreads();

    int lane = tid & 63;
    int wave = tid >> 6;
    int half = lane >> 5;
    int k = lane & 31;
    int gpair = blockIdx.x * 4 + wave;
    int npairs = gridDim.x * 4;
    float b3v = b3[0];
    for (int p = gpair; p * 2 < BATCH; p += npairs) {
        int r = p * 2 + half;
        float acc = b2l[k];
#pragma unroll
        for (int j = 0; j < 64; ++j)
            acc += H1[(size_t)r * 64 + j] * Wl[j * 32 + k];
        acc = acc * w3l[k];
#pragma unroll
        for (int off = 16; off; off >>= 1)
            acc += __shfl_xor(acc, off, 64);
        if (k == 0) out[r] = acc + b3v;
    }
}

// ---------------------------------------------------------------------------
extern "C" void kernel_launch(void* const* d_in, const int* in_sizes, int n_in,
                              void* d_out, int out_size, void* d_ws, size_t ws_size,
                              hipStream_t stream) {
    const int*   userIdx = (const int*)  d_in[0];
    const int*   itemIdx = (const int*)  d_in[1];
    const int*   lap_rows= (const int*)  d_in[2];
    const int*   lap_cols= (const int*)  d_in[3];
    const float* lap_vals= (const float*)d_in[4];
    const float* uEmb    = (const float*)d_in[5];
    const float* iEmb    = (const float*)d_in[6];
    const float* gW0     = (const float*)d_in[7];
    const float* gb0     = (const float*)d_in[8];
    const float* gW1     = (const float*)d_in[9];
    const float* gb1     = (const float*)d_in[10];
    const float* W1      = (const float*)d_in[11];
    const float* b1      = (const float*)d_in[12];
    const float* W2      = (const float*)d_in[13];
    const float* b2      = (const float*)d_in[14];
    const float* W3      = (const float*)d_in[15];
    const float* b3      = (const float*)d_in[16];
    float* out = (float*)d_out;

    const size_t NF = (size_t)N_NODES * EMB;              // 9.6M elements
    char* w = (char*)d_ws;
    unsigned short* bufA = (unsigned short*)w;            // feat0h then feat1h (19.2 MB)
    unsigned short* bufB = bufA + NF;                     // feat2h (19.2 MB)
    float* h       = (float*)(bufB + NF);                 // fp32 [N_NODES,64] (38.4 MB)
    int2*  packed  = (int2*)(h + NF);                     // 19.2 MB
    int*   row_ptr = (int*)(packed + NNZ);                // N_NODES+1
    int*   offs    = row_ptr + (N_NODES + 1);             // N_NODES
    int*   bsums   = offs + N_NODES;                      // 1024
    // E/H1 overlay h (h dead after second gemm64)
    unsigned short* E  = (unsigned short*)h;              // [BATCH,384] bf16 (12.6 MB)
    float* H1 = (float*)(E + (size_t)BATCH * D_CAT);      // [BATCH,64] fp32

    const int SCAN_NB   = (N_NODES + 1023) / 1024;        // 147
    const int edge_grid = (NNZ + 255) / 256;              // 9375
    const int spmm_grid = (N_NODES + 3) / 4;              // 37500
    const int gemm_grid = (N_NODES + 63) / 64;            // 2344
    const int cvt_grid  = (int)((NF / 4 + 255) / 256);    // 9375

    // ---- Build CSR (shared by both layers)
    hipMemsetAsync(offs, 0, N_NODES * sizeof(int), stream);
    hist_rows<<<edge_grid, 256, 0, stream>>>(lap_rows, offs, NNZ);
    scan1<<<SCAN_NB, 1024, 0, stream>>>(offs, row_ptr, bsums, N_NODES);
    scan2<<<1, 1024, 0, stream>>>(bsums, SCAN_NB);
    scan3<<<SCAN_NB, 1024, 0, stream>>>(row_ptr, offs, bsums, N_NODES, NNZ);
    scatter_edges<<<edge_grid, 256, 0, stream>>>(lap_rows, lap_cols, lap_vals,
                                                 offs, packed, NNZ);

    // ---- feat0h = bf16(concat(uEmb, iEmb))
    cvt_feat0<<<cvt_grid, 256, 0, stream>>>((const float4*)uEmb, NUM_USERS * EMB / 4,
                                            (const float4*)iEmb, NUM_ITEMS * EMB / 4,
                                            (ushort4*)bufA);

    // ---- Layer 1: h = (L+I)@feat0 ; feat1h = bf16(relu(h@gW0+gb0))
    spmm_csr<<<spmm_grid, 256, 0, stream>>>(row_ptr, packed, (const unsigned int*)bufA,
                                            (float2*)h, N_NODES);
    gemm64_relu_bf16<<<gemm_grid, 256, 0, stream>>>(h, gW0, gb0, bufA, N_NODES);

    // ---- Layer 2: h = (L+I)@feat1 ; feat2h = bf16(relu(h@gW1+gb1))
    spmm_csr<<<spmm_grid, 256, 0, stream>>>(row_ptr, packed, (const unsigned int*)bufA,
                                            (float2*)h, N_NODES);
    gemm64_relu_bf16<<<gemm_grid, 256, 0, stream>>>(h, gW1, gb1, bufB, N_NODES);

    // ---- Gather per-sample concatenated features (E overlays h)
    gather_e<<<BATCH, 384, 0, stream>>>(userIdx, itemIdx, uEmb, iEmb, bufA, bufB, E);

    // ---- MLP
    gemm384_bf16_relu<<<(BATCH + 63) / 64, 256, 0, stream>>>(E, W1, b1, H1, BATCH);
    mlp23<<<512, 256, 0, stream>>>(H1, W2, b2, W3, b3, out);
}